// Round 2
// baseline (455.288 us; speedup 1.0000x reference)
//
#include <hip/hip_runtime.h>
#include <math.h>

typedef unsigned short u16;
typedef unsigned int u32;

#define NBATCH 16
#define NCH    256
#define NPIX   4096
#define NHEAD  4
#define HDIM   32
#define NMEM   4
#define HID    128
#define OC3    384

__device__ __forceinline__ float bf2f(u16 u){ return __uint_as_float(((u32)u)<<16); }
__device__ __forceinline__ u16 f2bf(float f){
  u32 x = __float_as_uint(f);
  x += 0x7fffu + ((x>>16)&1u);          // RNE
  return (u16)(x>>16);
}
__device__ __forceinline__ void unpack8(int4 v, float* o){
  u32 a=(u32)v.x, b=(u32)v.y, c=(u32)v.z, d=(u32)v.w;
  o[0]=__uint_as_float(a<<16); o[1]=__uint_as_float(a&0xffff0000u);
  o[2]=__uint_as_float(b<<16); o[3]=__uint_as_float(b&0xffff0000u);
  o[4]=__uint_as_float(c<<16); o[5]=__uint_as_float(c&0xffff0000u);
  o[6]=__uint_as_float(d<<16); o[7]=__uint_as_float(d&0xffff0000u);
}

// ---------------------------------------------------------------------------
// K2: qkv[b,o,n] = r[b,n] * sum_c (w_qkv[o,c]*g_in[c]) * x[b,c,n]
// r[b,n] = 16/max(||x[b,:,n]||,1e-12) computed inline from the B tiles.
// fp32 in, bf16 out. 128x128 tile, 8x8 per thread, fp32 accum.
// ---------------------------------------------------------------------------
__global__ __launch_bounds__(256) void k_qkv(const float* __restrict__ x,
                                             const float* __restrict__ wqkv,
                                             const float* __restrict__ gin,
                                             u16* __restrict__ qkv)
{
  __shared__ float As[32][136];   // [c][o] transposed, pad 136
  __shared__ float Bs[32][140];   // [c][n], pad 140 (float4-aligned rows)
  const int t  = threadIdx.x;
  const int n0 = blockIdx.x*128;
  const int o0 = blockIdx.y*128;
  const int b  = blockIdx.z;
  const int to = t>>4, tn = t&15;
  const int o8 = to*8, n8 = tn*8;
  const int la_o = t>>1,  la_c = (t&1)*16;   // A: 128x32, 16/thread
  const int lb_k = t&31,  lb_n = (t>>5)*16;  // B: 32x128, 16/thread
  const float* xp = x + (size_t)b*NCH*NPIX + n0;

  float acc[8][8] = {};
  float ssq[8] = {};

  for (int c0=0; c0<NCH; c0+=32){
    { // stage A (w_qkv * g_in), transposed
      const float* pw = wqkv + (size_t)(o0+la_o)*NCH + c0 + la_c;
      const float* pg = gin + c0 + la_c;
      float wv[16], gv[16];
      #pragma unroll
      for (int u=0;u<4;u++){
        *(float4*)&wv[u*4] = *(const float4*)(pw + u*4);
        *(float4*)&gv[u*4] = *(const float4*)(pg + u*4);
      }
      #pragma unroll
      for (int j=0;j<16;j++) As[la_c+j][la_o] = wv[j]*gv[j];
    }
    { // stage B (raw x)
      const float* px = xp + (size_t)(c0+lb_k)*NPIX + lb_n;
      #pragma unroll
      for (int u=0;u<4;u++)
        *(float4*)&Bs[lb_k][lb_n+u*4] = *(const float4*)(px + u*4);
    }
    __syncthreads();
    #pragma unroll 8
    for (int k=0;k<32;k++){
      float av[8] __attribute__((aligned(16)));
      float bv[8] __attribute__((aligned(16)));
      *(float4*)&av[0] = *(const float4*)&As[k][o8];
      *(float4*)&av[4] = *(const float4*)&As[k][o8+4];
      *(float4*)&bv[0] = *(const float4*)&Bs[k][n8];
      *(float4*)&bv[4] = *(const float4*)&Bs[k][n8+4];
      #pragma unroll
      for (int j=0;j<8;j++) ssq[j] += bv[j]*bv[j];
      #pragma unroll
      for (int i=0;i<8;i++)
        #pragma unroll
        for (int j=0;j<8;j++) acc[i][j] += av[i]*bv[j];
    }
    __syncthreads();
  }
  float rinv[8];
  #pragma unroll
  for (int j=0;j<8;j++) rinv[j] = 16.0f / fmaxf(sqrtf(ssq[j]), 1e-12f);
  u16* qp = qkv + (size_t)(b*OC3 + o0 + o8)*NPIX + n0 + n8;
  #pragma unroll
  for (int i=0;i<8;i++){
    u32 w[4];
    #pragma unroll
    for (int q=0;q<4;q++){
      u16 lo = f2bf(acc[i][2*q  ]*rinv[2*q  ]);
      u16 hi = f2bf(acc[i][2*q+1]*rinv[2*q+1]);
      w[q] = (u32)lo | ((u32)hi<<16);
    }
    *(int4*)(qp + (size_t)i*NPIX) = make_int4((int)w[0],(int)w[1],(int)w[2],(int)w[3]);
  }
}

// ---------------------------------------------------------------------------
// K3: softmax over head_dim (32) per (b,h,n), * HD^-0.5, in place on q rows.
// ---------------------------------------------------------------------------
__global__ __launch_bounds__(256) void k_qsm(u16* __restrict__ qkv)
{
  int idx = blockIdx.x*256 + threadIdx.x;   // ((b*4+h)*4096 + n)
  int n  = idx & 4095;
  int bh = idx >> 12;
  int b = bh >> 2, h = bh & 3;
  u16* p = qkv + (size_t)(b*OC3 + h*HDIM)*NPIX + n;
  float v[32];
  float m = -1e30f;
  #pragma unroll
  for (int d=0;d<32;d++){ v[d] = bf2f(p[(size_t)d*NPIX]); m = fmaxf(m, v[d]); }
  float s = 0.f;
  #pragma unroll
  for (int d=0;d<32;d++){ v[d] = __expf(v[d]-m); s += v[d]; }
  float inv = 0.17677669529663687f / s;     // HD^-0.5 / sum
  #pragma unroll
  for (int d=0;d<32;d++) p[(size_t)d*NPIX] = f2bf(v[d]*inv);
}

// ---------------------------------------------------------------------------
// K4: softmax over tokens (4 mem + 4096) per (b,h,d) row; in place on k rows,
// memory-token results to ksm (fp32).
// ---------------------------------------------------------------------------
__global__ __launch_bounds__(256) void k_ksm(u16* __restrict__ qkv,
                                             const float* __restrict__ memkv,
                                             float* __restrict__ ksm)
{
  __shared__ float row[4096];
  __shared__ float redm[4], reds[4];
  const int rid = blockIdx.x;               // (b*4+h)*32 + d
  const int d = rid & 31, h = (rid>>5)&3, b = rid>>7;
  u16* p = qkv + (size_t)(b*OC3 + HID + h*HDIM + d)*NPIX;
  const int t = threadIdx.x;
  float lm = -1e30f;
  for (int i=t;i<4096;i+=256){ float v = bf2f(p[i]); row[i]=v; lm = fmaxf(lm,v); }
  float mv[4];
  #pragma unroll
  for (int m=0;m<4;m++){ mv[m] = memkv[(h*HDIM+d)*NMEM + m]; lm = fmaxf(lm, mv[m]); }
  #pragma unroll
  for (int s=32;s>0;s>>=1) lm = fmaxf(lm, __shfl_down(lm, s, 64));
  if ((t&63)==0) redm[t>>6] = lm;
  __syncthreads();
  const float M = fmaxf(fmaxf(redm[0],redm[1]), fmaxf(redm[2],redm[3]));
  float ls = 0.f;
  for (int i=t;i<4096;i+=256) ls += __expf(row[i]-M);
  #pragma unroll
  for (int s=32;s>0;s>>=1) ls += __shfl_down(ls, s, 64);
  if ((t&63)==0) reds[t>>6] = ls;
  __syncthreads();
  float S = reds[0]+reds[1]+reds[2]+reds[3];
  #pragma unroll
  for (int m=0;m<4;m++) S += __expf(mv[m]-M);
  const float inv = 1.0f/S;
  for (int i=t;i<4096;i+=256) p[i] = f2bf(__expf(row[i]-M)*inv);
  if (t<4) ksm[rid*NMEM + t] = __expf(mv[t]-M)*inv;
}

// ---------------------------------------------------------------------------
// K5: ctx[b,h,d,e] = sum_tokens ks[d,n]*v[e,n]  (partials over 8 n-splits)
// block = 1 wave, 4x4 per thread.
// ---------------------------------------------------------------------------
__global__ __launch_bounds__(64) void k_ctx(const u16* __restrict__ qkv,
                                            const float* __restrict__ memkv,
                                            const float* __restrict__ ksm,
                                            float* __restrict__ ctxp)
{
  __shared__ float Ks[32][132];
  __shared__ float Vs[32][132];
  const int bh = blockIdx.x;                // 0..63
  const int s  = blockIdx.y;                // 0..7
  const int b = bh>>2, h = bh&3;
  const int t = threadIdx.x;                // 0..63
  const int d0 = (t>>3)*4, e0 = (t&7)*4;
  float acc[4][4] = {};
  if (s==0){
    #pragma unroll
    for (int m=0;m<4;m++){
      float km[4];
      #pragma unroll
      for (int pi=0;pi<4;pi++) km[pi] = ksm[(bh*HDIM + d0+pi)*NMEM + m];
      #pragma unroll
      for (int q=0;q<4;q++){
        float vm = memkv[((NHEAD+h)*HDIM + e0+q)*NMEM + m];
        #pragma unroll
        for (int pi=0;pi<4;pi++) acc[pi][q] += km[pi]*vm;
      }
    }
  }
  const u16* kb = qkv + (size_t)(b*OC3 +   HID + h*HDIM)*NPIX;
  const u16* vb = qkv + (size_t)(b*OC3 + 2*HID + h*HDIM)*NPIX;
  const int lr = t>>1, lseg = (t&1)*64;
  for (int n0 = s*512; n0 < s*512+512; n0 += 128){
    const u16* kp = kb + (size_t)lr*NPIX + n0 + lseg;
    const u16* vp = vb + (size_t)lr*NPIX + n0 + lseg;
    #pragma unroll
    for (int u=0;u<8;u++){
      int4 kv = *(const int4*)(kp + u*8);
      int4 vv = *(const int4*)(vp + u*8);
      float kf[8], vf[8];
      unpack8(kv,kf); unpack8(vv,vf);
      *(float4*)&Ks[lr][lseg+u*8]   = make_float4(kf[0],kf[1],kf[2],kf[3]);
      *(float4*)&Ks[lr][lseg+u*8+4] = make_float4(kf[4],kf[5],kf[6],kf[7]);
      *(float4*)&Vs[lr][lseg+u*8]   = make_float4(vf[0],vf[1],vf[2],vf[3]);
      *(float4*)&Vs[lr][lseg+u*8+4] = make_float4(vf[4],vf[5],vf[6],vf[7]);
    }
    __syncthreads();
    #pragma unroll 4
    for (int nn=0;nn<128;nn+=4){
      float kq[4][4] __attribute__((aligned(16)));
      float vq[4][4] __attribute__((aligned(16)));
      #pragma unroll
      for (int pi=0;pi<4;pi++) *(float4*)kq[pi] = *(const float4*)&Ks[d0+pi][nn];
      #pragma unroll
      for (int q=0;q<4;q++)    *(float4*)vq[q]  = *(const float4*)&Vs[e0+q][nn];
      #pragma unroll
      for (int pi=0;pi<4;pi++)
        #pragma unroll
        for (int q=0;q<4;q++)
          acc[pi][q] += kq[pi][0]*vq[q][0] + kq[pi][1]*vq[q][1]
                      + kq[pi][2]*vq[q][2] + kq[pi][3]*vq[q][3];
    }
    __syncthreads();
  }
  #pragma unroll
  for (int pi=0;pi<4;pi++)
    *(float4*)(ctxp + (size_t)(s*64+bh)*1024 + (d0+pi)*32 + e0) =
      make_float4(acc[pi][0],acc[pi][1],acc[pi][2],acc[pi][3]);
}

__global__ __launch_bounds__(256) void k_ctxred(const float* __restrict__ ctxp,
                                                float* __restrict__ ctx)
{
  const int bh = blockIdx.x, t = threadIdx.x;
  float4 s = make_float4(0.f,0.f,0.f,0.f);
  #pragma unroll
  for (int sp=0; sp<8; sp++){
    float4 v = *(const float4*)(ctxp + (size_t)(sp*64+bh)*1024 + t*4);
    s.x+=v.x; s.y+=v.y; s.z+=v.z; s.w+=v.w;
  }
  *(float4*)(ctx + (size_t)bh*1024 + t*4) = s;
}

// ---------------------------------------------------------------------------
// K6: ao[b,h*32+e,n] = sum_d ctx[b,h,d,e]*qs[b,h*32+d,n]
// ctx addresses are lane-invariant -> scalar-load path.
// ---------------------------------------------------------------------------
__global__ __launch_bounds__(256) void k_attnout(const u16* __restrict__ qkv,
                                                 const float* __restrict__ ctx,
                                                 u16* __restrict__ ao)
{
  const int nc = blockIdx.x, h = blockIdx.y, b = blockIdx.z;
  const int bh = (b<<2) + h;
  const int n = nc*256 + threadIdx.x;
  const float* C = ctx + (size_t)bh*1024;
  const u16* qp = qkv + (size_t)(b*OC3 + h*HDIM)*NPIX + n;
  float qv[32];
  #pragma unroll
  for (int d=0;d<32;d++) qv[d] = bf2f(qp[(size_t)d*NPIX]);
  u16* op = ao + (size_t)(b*HID + h*HDIM)*NPIX + n;
  for (int eb=0;eb<8;eb++){
    float s0=0.f,s1=0.f,s2=0.f,s3=0.f;
    #pragma unroll
    for (int d=0;d<32;d++){
      float4 cv = *(const float4*)(C + d*32 + eb*4);
      float qd = qv[d];
      s0 += cv.x*qd; s1 += cv.y*qd; s2 += cv.z*qd; s3 += cv.w*qd;
    }
    op[(size_t)(eb*4+0)*NPIX] = f2bf(s0);
    op[(size_t)(eb*4+1)*NPIX] = f2bf(s1);
    op[(size_t)(eb*4+2)*NPIX] = f2bf(s2);
    op[(size_t)(eb*4+3)*NPIX] = f2bf(s3);
  }
}

// ---------------------------------------------------------------------------
// K7: y = w_out@ao + b_out, then rms_norm over c (g_out), fp32 out.
// w_out converted fp32->bf16 pairs into LDS, XOR-swizzled (conflict-free for
// the c-strided lane pattern). Column sum-of-squares via shfl_xor over the
// 32-lane c-coverage (half-wave groups share the same column set).
// ---------------------------------------------------------------------------
__global__ __launch_bounds__(256,1) void k_out(const u16* __restrict__ ao,
                                               const float* __restrict__ wout,
                                               const float* __restrict__ bout,
                                               const float* __restrict__ gout,
                                               float* __restrict__ out)
{
  __shared__ float aos[128][68];
  __shared__ u32 wl[16384];        // wl[c*64 + (op^(c&31))] = pair(o=2op,2op+1)
  const int t  = threadIdx.x;
  const int n0 = blockIdx.x*64;
  const int b  = blockIdx.y;
  #pragma unroll 8
  for (int rr=0; rr<64; rr++){
    int gidx = rr*256 + t;
    int c = gidx >> 6, op = gidx & 63;
    float2 wp = *(const float2*)(wout + 2*(size_t)gidx);
    wl[c*64 + (op ^ (c & 31))] = (u32)f2bf(wp.x) | ((u32)f2bf(wp.y)<<16);
  }
  {
    const int o = t>>1, seg = (t&1)*32;
    const u16* ap = ao + (size_t)(b*HID + o)*NPIX + n0 + seg;
    #pragma unroll
    for (int u=0;u<4;u++){
      int4 av = *(const int4*)(ap + u*8);
      float f[8]; unpack8(av, f);
      *(float4*)&aos[o][seg+u*8]   = make_float4(f[0],f[1],f[2],f[3]);
      *(float4*)&aos[o][seg+u*8+4] = make_float4(f[4],f[5],f[6],f[7]);
    }
  }
  __syncthreads();
  const int cg = t & 31;          // thread's c set: cg + 32*i
  const int n8 = (t>>5)*8;
  float acc[8][8] = {};
  #pragma unroll 2
  for (int op=0; op<64; op++){
    float w0[8], w1[8];
    #pragma unroll
    for (int i=0;i<8;i++){
      u32 wu = wl[(cg+32*i)*64 + (op^cg)];
      w0[i] = __uint_as_float(wu<<16);
      w1[i] = __uint_as_float(wu & 0xffff0000u);
    }
    float a0[8] __attribute__((aligned(16)));
    float a1[8] __attribute__((aligned(16)));
    *(float4*)&a0[0] = *(const float4*)&aos[2*op  ][n8];
    *(float4*)&a0[4] = *(const float4*)&aos[2*op  ][n8+4];
    *(float4*)&a1[0] = *(const float4*)&aos[2*op+1][n8];
    *(float4*)&a1[4] = *(const float4*)&aos[2*op+1][n8+4];
    #pragma unroll
    for (int i=0;i<8;i++)
      #pragma unroll
      for (int j=0;j<8;j++) acc[i][j] += w0[i]*a0[j] + w1[i]*a1[j];
  }
  float ss[8] = {};
  #pragma unroll
  for (int i=0;i<8;i++){
    float bi = bout[cg+32*i];
    #pragma unroll
    for (int j=0;j<8;j++){ acc[i][j] += bi; ss[j] += acc[i][j]*acc[i][j]; }
  }
  #pragma unroll
  for (int m=1;m<32;m<<=1){
    #pragma unroll
    for (int j=0;j<8;j++) ss[j] += __shfl_xor(ss[j], m, 64);
  }
  float rinv[8];
  #pragma unroll
  for (int j=0;j<8;j++) rinv[j] = 16.0f / fmaxf(sqrtf(ss[j]), 1e-12f);
  #pragma unroll
  for (int i=0;i<8;i++){
    float gi = gout[cg+32*i];
    float* po = out + (size_t)(b*NCH + cg + 32*i)*NPIX + n0 + n8;
    float4 r0 = make_float4(acc[i][0]*rinv[0]*gi, acc[i][1]*rinv[1]*gi,
                            acc[i][2]*rinv[2]*gi, acc[i][3]*rinv[3]*gi);
    float4 r1 = make_float4(acc[i][4]*rinv[4]*gi, acc[i][5]*rinv[5]*gi,
                            acc[i][6]*rinv[6]*gi, acc[i][7]*rinv[7]*gi);
    *(float4*)po     = r0;
    *(float4*)(po+4) = r1;
  }
}

// ---------------------------------------------------------------------------
extern "C" void kernel_launch(void* const* d_in, const int* in_sizes, int n_in,
                              void* d_out, int out_size, void* d_ws, size_t ws_size,
                              hipStream_t stream)
{
  const float* x     = (const float*)d_in[0];
  const float* gin   = (const float*)d_in[1];
  const float* memkv = (const float*)d_in[2];
  const float* wqkv  = (const float*)d_in[3];
  const float* wout  = (const float*)d_in[4];
  const float* bout  = (const float*)d_in[5];
  const float* gout  = (const float*)d_in[6];
  float* out = (float*)d_out;

  char* ws = (char*)d_ws;
  u16*   qkv  = (u16*)  (ws);                       // 16*384*4096*2   = 50,331,648
  float* ksm  = (float*)(ws + 50331648);            // 2048*4*4        =     32,768
  float* ctxp = (float*)(ws + 50364416);            // 8*64*1024*4     =  2,097,152
  float* ctx  = (float*)(ws + 52461568);            // 64*1024*4       =    262,144
  u16*   ao   = (u16*)  (ws + 52723712);            // 16*128*4096*2   = 16,777,216
                                                    // total 69,500,928 B

  hipLaunchKernelGGL(k_qkv,    dim3(32,3,16), dim3(256), 0, stream, x, wqkv, gin, qkv);
  hipLaunchKernelGGL(k_qsm,    dim3(1024),    dim3(256), 0, stream, qkv);
  hipLaunchKernelGGL(k_ksm,    dim3(2048),    dim3(256), 0, stream, qkv, memkv, ksm);
  hipLaunchKernelGGL(k_ctx,    dim3(64,8),    dim3(64),  0, stream, qkv, memkv, ksm, ctxp);
  hipLaunchKernelGGL(k_ctxred, dim3(64),      dim3(256), 0, stream, ctxp, ctx);
  hipLaunchKernelGGL(k_attnout,dim3(16,4,16), dim3(256), 0, stream, qkv, ctx, ao);
  hipLaunchKernelGGL(k_out,    dim3(64,16),   dim3(256), 0, stream, ao, wout, bout, gout, out);
}

// Round 3
// 266.057 us; speedup vs baseline: 1.7112x; 1.7112x over previous
//
#include <hip/hip_runtime.h>
#include <math.h>

typedef unsigned short u16;
typedef unsigned int u32;

#define NBATCH 16
#define NCH    256
#define NPIX   4096
#define NHEAD  4
#define HDIM   32
#define NMEM   4
#define HID    128
#define OC3    384

typedef __bf16 bf16x8 __attribute__((ext_vector_type(8)));
typedef float  f32x4  __attribute__((ext_vector_type(4)));

__device__ __forceinline__ float bf2f(u16 u){ return __uint_as_float(((u32)u)<<16); }
__device__ __forceinline__ u16 f2bf(float f){
  u32 x = __float_as_uint(f);
  x += 0x7fffu + ((x>>16)&1u);          // RNE
  return (u16)(x>>16);
}
__device__ __forceinline__ void unpack8(int4 v, float* o){
  u32 a=(u32)v.x, b=(u32)v.y, c=(u32)v.z, d=(u32)v.w;
  o[0]=__uint_as_float(a<<16); o[1]=__uint_as_float(a&0xffff0000u);
  o[2]=__uint_as_float(b<<16); o[3]=__uint_as_float(b&0xffff0000u);
  o[4]=__uint_as_float(c<<16); o[5]=__uint_as_float(c&0xffff0000u);
  o[6]=__uint_as_float(d<<16); o[7]=__uint_as_float(d&0xffff0000u);
}
// async global->LDS, 16B per lane; LDS dest = wave-uniform base + lane*16
__device__ __forceinline__ void async16(u16* lds, const u16* g){
  __builtin_amdgcn_global_load_lds((const __attribute__((address_space(1))) u32*)g,
                                   (__attribute__((address_space(3))) u32*)lds, 16, 0, 0);
}

// ---------------------------------------------------------------------------
// K0: pack wqb[o][c] = bf16(w_qkv*g_in), wob[c][e] = bf16(w_out)
// ---------------------------------------------------------------------------
__global__ __launch_bounds__(256) void k_pack(const float* __restrict__ wqkv,
                                              const float* __restrict__ gin,
                                              const float* __restrict__ wout,
                                              u16* __restrict__ wqb,
                                              u16* __restrict__ wob)
{
  int i = blockIdx.x*256 + threadIdx.x;
  if (i < OC3*NCH){ int c = i & 255; wqb[i] = f2bf(wqkv[i]*gin[c]); }
  else { int j = i - OC3*NCH; wob[j] = f2bf(wout[j]); }
}

// ---------------------------------------------------------------------------
// K1: rinv[b,n] = 16/max(||x[b,:,n]||,1e-12) (fp32) + transpose x -> bf16
// xT[b][n][c] (k-contiguous for MFMA B fragments).
// ---------------------------------------------------------------------------
__global__ __launch_bounds__(256) void k_prep(const float* __restrict__ x,
                                              u16* __restrict__ xT,
                                              float* __restrict__ rinvg)
{
  __shared__ u16 tile[64*264];    // [n][c], stride 264 u16 (528B: 16B-mult, bank-spread)
  __shared__ float ssql[4][64];
  const int t = threadIdx.x, lane = t&63, w = t>>6;
  const int n0 = blockIdx.x*64, b = blockIdx.y;
  const int cb = w*64;
  const float* xp = x + ((size_t)b*NCH + cb)*NPIX + n0 + lane;
  float ssq = 0.f;
  #pragma unroll
  for (int j=0;j<8;j++){
    u32 pk[4];
    #pragma unroll
    for (int q=0;q<4;q++){
      float v0 = xp[(size_t)(j*8+2*q  )*NPIX];
      float v1 = xp[(size_t)(j*8+2*q+1)*NPIX];
      ssq += v0*v0 + v1*v1;
      pk[q] = (u32)f2bf(v0) | ((u32)f2bf(v1)<<16);
    }
    *(int4*)&tile[lane*264 + cb + j*8] = make_int4((int)pk[0],(int)pk[1],(int)pk[2],(int)pk[3]);
  }
  ssql[w][lane] = ssq;
  __syncthreads();
  if (t < 64){
    float s = ssql[0][t]+ssql[1][t]+ssql[2][t]+ssql[3][t];
    rinvg[(size_t)b*NPIX + n0 + t] = 16.0f / fmaxf(sqrtf(s), 1e-12f);
  }
  const int nr = t>>2, ch = (t&3)*64;
  u16* op = xT + ((size_t)b*NPIX + n0 + nr)*NCH + ch;
  #pragma unroll
  for (int i=0;i<8;i++)
    *(int4*)(op + i*8) = *(const int4*)&tile[nr*264 + ch + i*8];
}

// ---------------------------------------------------------------------------
// K2: qkv[b,o,n] = rinv[b,n] * sum_c wqb[o,c] * xT[b,n,c]   (bf16 MFMA)
// 128x128 tile, 4 waves x (4x4 16x16x32 frags), BK=32, global_load_lds w=16.
// Chunk-slot XOR swizzle (slot = (quad + row>>1) & 3) -> bank-uniform b128.
// ---------------------------------------------------------------------------
__global__ __launch_bounds__(256) void k_qkv(const u16* __restrict__ wqb,
                                             const u16* __restrict__ xT,
                                             const float* __restrict__ rinvg,
                                             u16* __restrict__ qkv)
{
  __shared__ u16 As[128*32];      // [o][k], 64B rows
  __shared__ u16 Bs[128*32];      // [n][k]
  __shared__ u16 Ds[128*136];     // repack, stride 136 u16 (16B-mult)
  const int t = threadIdx.x, w = t>>6, lane = t&63;
  const int n0 = blockIdx.x*128, o0 = blockIdx.y*128, b = blockIdx.z;
  const int wm = (w&1)*64, wn = (w>>1)*64;
  const int qw = lane>>4, rr = lane&15;
  f32x4 acc[4][4];
  #pragma unroll
  for (int i=0;i<4;i++)
    #pragma unroll
    for (int j=0;j<4;j++) acc[i][j] = (f32x4){0.f,0.f,0.f,0.f};

  const u16* Ag = wqb + (size_t)o0*NCH;
  const u16* Bg = xT + ((size_t)b*NPIX + n0)*NCH;

  for (int c0=0; c0<NCH; c0+=32){
    #pragma unroll
    for (int j=0;j<2;j++){
      int rb = w*32 + j*16;
      int row = rb + (lane>>2);
      int gc  = ((lane&3) - (row>>1)) & 3;
      async16(&As[rb*32], Ag + (size_t)row*NCH + c0 + gc*8);
      async16(&Bs[rb*32], Bg + (size_t)row*NCH + c0 + gc*8);
    }
    __syncthreads();
    bf16x8 af[4], bfr[4];
    #pragma unroll
    for (int mf=0;mf<4;mf++){
      int row = wm + mf*16 + rr;
      int s = (qw + (row>>1)) & 3;
      af[mf] = *(const bf16x8*)&As[row*32 + s*8];
    }
    #pragma unroll
    for (int nf=0;nf<4;nf++){
      int row = wn + nf*16 + rr;
      int s = (qw + (row>>1)) & 3;
      bfr[nf] = *(const bf16x8*)&Bs[row*32 + s*8];
    }
    #pragma unroll
    for (int mf=0;mf<4;mf++)
      #pragma unroll
      for (int nf=0;nf<4;nf++)
        acc[mf][nf] = __builtin_amdgcn_mfma_f32_16x16x32_bf16(af[mf], bfr[nf], acc[mf][nf], 0, 0, 0);
    __syncthreads();
  }
  float rv[4];
  #pragma unroll
  for (int nf=0;nf<4;nf++) rv[nf] = rinvg[(size_t)b*NPIX + n0 + wn + nf*16 + rr];
  #pragma unroll
  for (int mf=0;mf<4;mf++)
    #pragma unroll
    for (int nf=0;nf<4;nf++)
      #pragma unroll
      for (int reg=0;reg<4;reg++){
        int row = wm + mf*16 + qw*4 + reg;
        int col = wn + nf*16 + rr;
        Ds[row*136 + col] = f2bf(acc[mf][nf][reg] * rv[nf]);
      }
  __syncthreads();
  const int ro = t>>1, sg = (t&1)*64;
  u16* qp = qkv + ((size_t)(b*OC3 + o0 + ro))*NPIX + n0 + sg;
  #pragma unroll
  for (int i=0;i<8;i++)
    *(int4*)(qp + i*8) = *(const int4*)&Ds[ro*136 + sg + i*8];
}

// ---------------------------------------------------------------------------
// K3: softmax over head_dim (32) per (b,h,n), * HD^-0.5, in place on q rows.
// ---------------------------------------------------------------------------
__global__ __launch_bounds__(256) void k_qsm(u16* __restrict__ qkv)
{
  int idx = blockIdx.x*256 + threadIdx.x;
  int n  = idx & 4095;
  int bh = idx >> 12;
  int b = bh >> 2, h = bh & 3;
  u16* p = qkv + (size_t)(b*OC3 + h*HDIM)*NPIX + n;
  float v[32];
  float m = -1e30f;
  #pragma unroll
  for (int d=0;d<32;d++){ v[d] = bf2f(p[(size_t)d*NPIX]); m = fmaxf(m, v[d]); }
  float s = 0.f;
  #pragma unroll
  for (int d=0;d<32;d++){ v[d] = __expf(v[d]-m); s += v[d]; }
  float inv = 0.17677669529663687f / s;
  #pragma unroll
  for (int d=0;d<32;d++) p[(size_t)d*NPIX] = f2bf(v[d]*inv);
}

// ---------------------------------------------------------------------------
// K4: softmax over tokens (4 mem + 4096) per (b,h,d) row.
// ---------------------------------------------------------------------------
__global__ __launch_bounds__(256) void k_ksm(u16* __restrict__ qkv,
                                             const float* __restrict__ memkv,
                                             float* __restrict__ ksm)
{
  __shared__ float row[4096];
  __shared__ float redm[4], reds[4];
  const int rid = blockIdx.x;
  const int d = rid & 31, h = (rid>>5)&3, b = rid>>7;
  u16* p = qkv + (size_t)(b*OC3 + HID + h*HDIM + d)*NPIX;
  const int t = threadIdx.x;
  float lm = -1e30f;
  for (int i=t;i<4096;i+=256){ float v = bf2f(p[i]); row[i]=v; lm = fmaxf(lm,v); }
  float mv[4];
  #pragma unroll
  for (int m=0;m<4;m++){ mv[m] = memkv[(h*HDIM+d)*NMEM + m]; lm = fmaxf(lm, mv[m]); }
  #pragma unroll
  for (int s=32;s>0;s>>=1) lm = fmaxf(lm, __shfl_down(lm, s, 64));
  if ((t&63)==0) redm[t>>6] = lm;
  __syncthreads();
  const float M = fmaxf(fmaxf(redm[0],redm[1]), fmaxf(redm[2],redm[3]));
  float ls = 0.f;
  for (int i=t;i<4096;i+=256) ls += __expf(row[i]-M);
  #pragma unroll
  for (int s=32;s>0;s>>=1) ls += __shfl_down(ls, s, 64);
  if ((t&63)==0) reds[t>>6] = ls;
  __syncthreads();
  float S = reds[0]+reds[1]+reds[2]+reds[3];
  #pragma unroll
  for (int m=0;m<4;m++) S += __expf(mv[m]-M);
  const float inv = 1.0f/S;
  for (int i=t;i<4096;i+=256) p[i] = f2bf(__expf(row[i]-M)*inv);
  if (t<4) ksm[rid*NMEM + t] = __expf(mv[t]-M)*inv;
}

// ---------------------------------------------------------------------------
// K5: ctx[b,h,d,e] = sum_tokens ks[d,n]*v[e,n]  (partials over 8 n-splits)
// ---------------------------------------------------------------------------
__global__ __launch_bounds__(64) void k_ctx(const u16* __restrict__ qkv,
                                            const float* __restrict__ memkv,
                                            const float* __restrict__ ksm,
                                            float* __restrict__ ctxp)
{
  __shared__ float Ks[32][132];
  __shared__ float Vs[32][132];
  const int bh = blockIdx.x;
  const int s  = blockIdx.y;
  const int b = bh>>2, h = bh&3;
  const int t = threadIdx.x;
  const int d0 = (t>>3)*4, e0 = (t&7)*4;
  float acc[4][4] = {};
  if (s==0){
    #pragma unroll
    for (int m=0;m<4;m++){
      float km[4];
      #pragma unroll
      for (int pi=0;pi<4;pi++) km[pi] = ksm[(bh*HDIM + d0+pi)*NMEM + m];
      #pragma unroll
      for (int q=0;q<4;q++){
        float vm = memkv[((NHEAD+h)*HDIM + e0+q)*NMEM + m];
        #pragma unroll
        for (int pi=0;pi<4;pi++) acc[pi][q] += km[pi]*vm;
      }
    }
  }
  const u16* kb = qkv + (size_t)(b*OC3 +   HID + h*HDIM)*NPIX;
  const u16* vb = qkv + (size_t)(b*OC3 + 2*HID + h*HDIM)*NPIX;
  const int lr = t>>1, lseg = (t&1)*64;
  for (int n0 = s*512; n0 < s*512+512; n0 += 128){
    const u16* kp = kb + (size_t)lr*NPIX + n0 + lseg;
    const u16* vp = vb + (size_t)lr*NPIX + n0 + lseg;
    #pragma unroll
    for (int u=0;u<8;u++){
      int4 kv = *(const int4*)(kp + u*8);
      int4 vv = *(const int4*)(vp + u*8);
      float kf[8], vf[8];
      unpack8(kv,kf); unpack8(vv,vf);
      *(float4*)&Ks[lr][lseg+u*8]   = make_float4(kf[0],kf[1],kf[2],kf[3]);
      *(float4*)&Ks[lr][lseg+u*8+4] = make_float4(kf[4],kf[5],kf[6],kf[7]);
      *(float4*)&Vs[lr][lseg+u*8]   = make_float4(vf[0],vf[1],vf[2],vf[3]);
      *(float4*)&Vs[lr][lseg+u*8+4] = make_float4(vf[4],vf[5],vf[6],vf[7]);
    }
    __syncthreads();
    #pragma unroll 4
    for (int nn=0;nn<128;nn+=4){
      float kq[4][4] __attribute__((aligned(16)));
      float vq[4][4] __attribute__((aligned(16)));
      #pragma unroll
      for (int pi=0;pi<4;pi++) *(float4*)kq[pi] = *(const float4*)&Ks[d0+pi][nn];
      #pragma unroll
      for (int q=0;q<4;q++)    *(float4*)vq[q]  = *(const float4*)&Vs[e0+q][nn];
      #pragma unroll
      for (int pi=0;pi<4;pi++)
        #pragma unroll
        for (int q=0;q<4;q++)
          acc[pi][q] += kq[pi][0]*vq[q][0] + kq[pi][1]*vq[q][1]
                      + kq[pi][2]*vq[q][2] + kq[pi][3]*vq[q][3];
    }
    __syncthreads();
  }
  #pragma unroll
  for (int pi=0;pi<4;pi++)
    *(float4*)(ctxp + (size_t)(s*64+bh)*1024 + (d0+pi)*32 + e0) =
      make_float4(acc[pi][0],acc[pi][1],acc[pi][2],acc[pi][3]);
}

__global__ __launch_bounds__(256) void k_ctxred(const float* __restrict__ ctxp,
                                                float* __restrict__ ctx)
{
  const int bh = blockIdx.x, t = threadIdx.x;
  float4 s = make_float4(0.f,0.f,0.f,0.f);
  #pragma unroll
  for (int sp=0; sp<8; sp++){
    float4 v = *(const float4*)(ctxp + (size_t)(sp*64+bh)*1024 + t*4);
    s.x+=v.x; s.y+=v.y; s.z+=v.z; s.w+=v.w;
  }
  *(float4*)(ctx + (size_t)bh*1024 + t*4) = s;
}

// ---------------------------------------------------------------------------
// K6: aoT[b,n,h*32+e] = sum_d ctx[b,h,d,e]*qs[b,h*32+d,n]   (e-contiguous out)
// ---------------------------------------------------------------------------
__global__ __launch_bounds__(256) void k_attnout(const u16* __restrict__ qkv,
                                                 const float* __restrict__ ctx,
                                                 u16* __restrict__ aoT)
{
  const int nc = blockIdx.x, h = blockIdx.y, b = blockIdx.z;
  const int bh = (b<<2) + h;
  const int n = nc*256 + threadIdx.x;
  const float* C = ctx + (size_t)bh*1024;
  const u16* qp = qkv + (size_t)(b*OC3 + h*HDIM)*NPIX + n;
  float qv[32];
  #pragma unroll
  for (int d=0;d<32;d++) qv[d] = bf2f(qp[(size_t)d*NPIX]);
  float res[32];
  #pragma unroll
  for (int eb=0;eb<8;eb++){
    float s0=0.f,s1=0.f,s2=0.f,s3=0.f;
    #pragma unroll
    for (int d=0;d<32;d++){
      float4 cv = *(const float4*)(C + d*32 + eb*4);
      float qd = qv[d];
      s0 += cv.x*qd; s1 += cv.y*qd; s2 += cv.z*qd; s3 += cv.w*qd;
    }
    res[eb*4+0]=s0; res[eb*4+1]=s1; res[eb*4+2]=s2; res[eb*4+3]=s3;
  }
  u16* op = aoT + ((size_t)b*NPIX + n)*HID + h*HDIM;
  #pragma unroll
  for (int i=0;i<4;i++){
    u32 pk[4];
    #pragma unroll
    for (int q=0;q<4;q++)
      pk[q] = (u32)f2bf(res[i*8+2*q]) | ((u32)f2bf(res[i*8+2*q+1])<<16);
    *(int4*)(op + i*8) = make_int4((int)pk[0],(int)pk[1],(int)pk[2],(int)pk[3]);
  }
}

// ---------------------------------------------------------------------------
// K7: out[b,c,n] = rms_c( wob[c,:] . aoT[b,n,:] + b_out ) * g_out  (bf16 MFMA)
// Tile 256c x 64n (full c per block -> in-block rms), 4 waves x (4x4 frags).
// ---------------------------------------------------------------------------
__global__ __launch_bounds__(256) void k_out(const u16* __restrict__ wob,
                                             const u16* __restrict__ aoT,
                                             const float* __restrict__ bout,
                                             const float* __restrict__ gout,
                                             float* __restrict__ out)
{
  __shared__ u16 As[256*32];      // [c][k]
  __shared__ u16 Bs[64*32];       // [n][k]
  __shared__ float ssql[4][64];
  const int t = threadIdx.x, w = t>>6, lane = t&63;
  const int n0 = blockIdx.x*64, b = blockIdx.y;
  const int qw = lane>>4, rr = lane&15;
  f32x4 acc[4][4];
  #pragma unroll
  for (int i=0;i<4;i++)
    #pragma unroll
    for (int j=0;j<4;j++) acc[i][j] = (f32x4){0.f,0.f,0.f,0.f};

  const u16* Bg = aoT + ((size_t)b*NPIX + n0)*HID;

  for (int k0=0; k0<HID; k0+=32){
    #pragma unroll
    for (int j=0;j<4;j++){
      int rb = w*64 + j*16;
      int row = rb + (lane>>2);
      int gc  = ((lane&3) - (row>>1)) & 3;
      async16(&As[rb*32], wob + (size_t)row*HID + k0 + gc*8);
    }
    {
      int rb = w*16;
      int row = rb + (lane>>2);
      int gc  = ((lane&3) - (row>>1)) & 3;
      async16(&Bs[rb*32], Bg + (size_t)row*HID + k0 + gc*8);
    }
    __syncthreads();
    bf16x8 af[4], bfr[4];
    #pragma unroll
    for (int mf=0;mf<4;mf++){
      int row = w*64 + mf*16 + rr;
      int s = (qw + (row>>1)) & 3;
      af[mf] = *(const bf16x8*)&As[row*32 + s*8];
    }
    #pragma unroll
    for (int nf=0;nf<4;nf++){
      int row = nf*16 + rr;
      int s = (qw + (row>>1)) & 3;
      bfr[nf] = *(const bf16x8*)&Bs[row*32 + s*8];
    }
    #pragma unroll
    for (int mf=0;mf<4;mf++)
      #pragma unroll
      for (int nf=0;nf<4;nf++)
        acc[mf][nf] = __builtin_amdgcn_mfma_f32_16x16x32_bf16(af[mf], bfr[nf], acc[mf][nf], 0, 0, 0);
    __syncthreads();
  }
  float pssq[4] = {0.f,0.f,0.f,0.f};
  #pragma unroll
  for (int mf=0;mf<4;mf++)
    #pragma unroll
    for (int reg=0;reg<4;reg++){
      int c = w*64 + mf*16 + qw*4 + reg;
      float bb = bout[c];
      #pragma unroll
      for (int nf=0;nf<4;nf++){
        float v = acc[mf][nf][reg] + bb;
        acc[mf][nf][reg] = v;
        pssq[nf] += v*v;
      }
    }
  #pragma unroll
  for (int nf=0;nf<4;nf++){
    pssq[nf] += __shfl_xor(pssq[nf], 16, 64);
    pssq[nf] += __shfl_xor(pssq[nf], 32, 64);
  }
  if (qw==0){
    #pragma unroll
    for (int nf=0;nf<4;nf++) ssql[w][nf*16+rr] = pssq[nf];
  }
  __syncthreads();
  float rv[4];
  #pragma unroll
  for (int nf=0;nf<4;nf++){
    int col = nf*16 + rr;
    float sm = ssql[0][col]+ssql[1][col]+ssql[2][col]+ssql[3][col];
    rv[nf] = 16.0f / fmaxf(sqrtf(sm), 1e-12f);
  }
  #pragma unroll
  for (int mf=0;mf<4;mf++)
    #pragma unroll
    for (int reg=0;reg<4;reg++){
      int c = w*64 + mf*16 + qw*4 + reg;
      float g = gout[c];
      float* po = out + ((size_t)(b*NCH + c))*NPIX + n0;
      #pragma unroll
      for (int nf=0;nf<4;nf++)
        po[nf*16 + rr] = acc[mf][nf][reg]*rv[nf]*g;
    }
}

// ---------------------------------------------------------------------------
extern "C" void kernel_launch(void* const* d_in, const int* in_sizes, int n_in,
                              void* d_out, int out_size, void* d_ws, size_t ws_size,
                              hipStream_t stream)
{
  const float* x     = (const float*)d_in[0];
  const float* gin   = (const float*)d_in[1];
  const float* memkv = (const float*)d_in[2];
  const float* wqkv  = (const float*)d_in[3];
  const float* wout  = (const float*)d_in[4];
  const float* bout  = (const float*)d_in[5];
  const float* gout  = (const float*)d_in[6];
  float* out = (float*)d_out;

  char* ws = (char*)d_ws;
  u16*   qkv   = (u16*)  (ws);                      // 50,331,648
  float* ksm   = (float*)(ws + 50331648);           //     32,768
  float* ctxp  = (float*)(ws + 50364416);           //  2,097,152
  float* ctx   = (float*)(ws + 52461568);           //    262,144
  u16*   xT    = (u16*)  (ws + 52723712);           // 33,554,432
  u16*   aoT   = xT;                                // alias: k_attnout runs after k_qkv consumed xT
  float* rinvg = (float*)(ws + 86278144);           //    262,144
  u16*   wqb   = (u16*)  (ws + 86540288);           //    196,608
  u16*   wob   = (u16*)  (ws + 86736896);           //     65,536  -> total 86,802,432

  hipLaunchKernelGGL(k_pack,   dim3(512),     dim3(256), 0, stream, wqkv, gin, wout, wqb, wob);
  hipLaunchKernelGGL(k_prep,   dim3(64,16),   dim3(256), 0, stream, x, xT, rinvg);
  hipLaunchKernelGGL(k_qkv,    dim3(32,3,16), dim3(256), 0, stream, wqb, xT, rinvg, qkv);
  hipLaunchKernelGGL(k_qsm,    dim3(1024),    dim3(256), 0, stream, qkv);
  hipLaunchKernelGGL(k_ksm,    dim3(2048),    dim3(256), 0, stream, qkv, memkv, ksm);
  hipLaunchKernelGGL(k_ctx,    dim3(64,8),    dim3(64),  0, stream, qkv, memkv, ksm, ctxp);
  hipLaunchKernelGGL(k_ctxred, dim3(64),      dim3(256), 0, stream, ctxp, ctx);
  hipLaunchKernelGGL(k_attnout,dim3(16,4,16), dim3(256), 0, stream, qkv, ctx, aoT);
  hipLaunchKernelGGL(k_out,    dim3(64,16),   dim3(256), 0, stream, wob, aoT, bout, gout, out);
}

// Round 4
// 211.736 us; speedup vs baseline: 2.1503x; 1.2565x over previous
//
#include <hip/hip_runtime.h>
#include <math.h>

typedef unsigned short u16;
typedef unsigned int u32;

#define NBATCH 16
#define NCH    256
#define NPIX   4096
#define NHEAD  4
#define HDIM   32
#define NMEM   4
#define HID    128
#define OC3    384
#define SCALE_Q 0.17677669529663687f

typedef __bf16 bf16x8 __attribute__((ext_vector_type(8)));
typedef float  f32x4  __attribute__((ext_vector_type(4)));

__device__ __forceinline__ float bf2f(u16 u){ return __uint_as_float(((u32)u)<<16); }
__device__ __forceinline__ u16 f2bf(float f){
  u32 x = __float_as_uint(f);
  x += 0x7fffu + ((x>>16)&1u);          // RNE
  return (u16)(x>>16);
}
__device__ __forceinline__ void unpack8(int4 v, float* o){
  u32 a=(u32)v.x, b=(u32)v.y, c=(u32)v.z, d=(u32)v.w;
  o[0]=__uint_as_float(a<<16); o[1]=__uint_as_float(a&0xffff0000u);
  o[2]=__uint_as_float(b<<16); o[3]=__uint_as_float(b&0xffff0000u);
  o[4]=__uint_as_float(c<<16); o[5]=__uint_as_float(c&0xffff0000u);
  o[6]=__uint_as_float(d<<16); o[7]=__uint_as_float(d&0xffff0000u);
}
// async global->LDS, 16B per lane; LDS dest = wave-uniform base + lane*16
__device__ __forceinline__ void async16(u16* lds, const u16* g){
  __builtin_amdgcn_global_load_lds((const __attribute__((address_space(1))) u32*)g,
                                   (__attribute__((address_space(3))) u32*)lds, 16, 0, 0);
}

// ---------------------------------------------------------------------------
// K0: pack wqb[o][c] = bf16(w_qkv*g_in), wob[c][e] = bf16(w_out)
// ---------------------------------------------------------------------------
__global__ __launch_bounds__(256) void k_pack(const float* __restrict__ wqkv,
                                              const float* __restrict__ gin,
                                              const float* __restrict__ wout,
                                              u16* __restrict__ wqb,
                                              u16* __restrict__ wob)
{
  int i = blockIdx.x*256 + threadIdx.x;
  if (i < OC3*NCH){ int c = i & 255; wqb[i] = f2bf(wqkv[i]*gin[c]); }
  else { int j = i - OC3*NCH; wob[j] = f2bf(wout[j]); }
}

// ---------------------------------------------------------------------------
// K1: fused rms-norm + transpose + QKV GEMM (bf16 MFMA) + q-softmax.
// Tile 384(o) x 64(n), 8 waves; wave w owns m-frags {w, w+8, w+16} -> one
// frag per o-group (q/k/v). x read once (fp32), transposed to LDS bf16.
// q rows get softmax over head_dim in the epilogue (all d in-block).
// ---------------------------------------------------------------------------
__global__ __launch_bounds__(512) void k_qkvx(const float* __restrict__ x,
                                              const u16* __restrict__ wqb,
                                              u16* __restrict__ qkv)
{
  __shared__ u16 Bx[64*264];      // [n][c] bf16, stride 264 u16 (16B-mult, bank-spread)
  __shared__ u16 As[384*32];      // [o][k-slice], 64B rows, slot-swizzled
  __shared__ u16 Ds[128*72];      // per-pass repack, stride 72 u16
  __shared__ float ssqp[8][64];
  __shared__ float rl[64];
  const int t = threadIdx.x, w = t>>6, lane = t&63;
  const int n0 = blockIdx.x*64, b = blockIdx.y;
  const int qw = lane>>4, rr = lane&15;

  // phase 1: load x (coalesced), bf16-transpose into Bx, per-n sum-of-squares
  {
    const float* xp = x + ((size_t)b*NCH + w*32)*NPIX + n0 + lane;
    float ssq = 0.f;
    #pragma unroll
    for (int j=0;j<4;j++){
      u32 pk[4];
      #pragma unroll
      for (int q=0;q<4;q++){
        float v0 = xp[(size_t)(j*8+2*q  )*NPIX];
        float v1 = xp[(size_t)(j*8+2*q+1)*NPIX];
        ssq += v0*v0 + v1*v1;
        pk[q] = (u32)f2bf(v0) | ((u32)f2bf(v1)<<16);
      }
      *(int4*)&Bx[lane*264 + w*32 + j*8] = make_int4((int)pk[0],(int)pk[1],(int)pk[2],(int)pk[3]);
    }
    ssqp[w][lane] = ssq;
  }
  __syncthreads();
  if (t < 64){
    float s = 0.f;
    #pragma unroll
    for (int g=0;g<8;g++) s += ssqp[g][t];
    rl[t] = 16.0f / fmaxf(sqrtf(s), 1e-12f);
  }

  f32x4 acc[3][4];
  #pragma unroll
  for (int p=0;p<3;p++)
    #pragma unroll
    for (int nf=0;nf<4;nf++) acc[p][nf] = (f32x4){0.f,0.f,0.f,0.f};

  // K-loop: 8 iterations over c
  for (int c0=0; c0<NCH; c0+=32){
    if (c0) __syncthreads();
    #pragma unroll
    for (int j=0;j<3;j++){
      int rb = w*48 + j*16;
      int row = rb + (lane>>2);
      int gc  = ((lane&3) - (row>>1)) & 3;
      async16(&As[rb*32], wqb + (size_t)row*NCH + c0 + gc*8);
    }
    __syncthreads();
    bf16x8 af[3], bfr[4];
    #pragma unroll
    for (int p=0;p<3;p++){
      int row = p*128 + w*16 + rr;
      int s = (qw + (row>>1)) & 3;
      af[p] = *(const bf16x8*)&As[row*32 + s*8];
    }
    #pragma unroll
    for (int nf=0;nf<4;nf++)
      bfr[nf] = *(const bf16x8*)&Bx[(nf*16+rr)*264 + c0 + qw*8];
    #pragma unroll
    for (int p=0;p<3;p++)
      #pragma unroll
      for (int nf=0;nf<4;nf++)
        acc[p][nf] = __builtin_amdgcn_mfma_f32_16x16x32_bf16(af[p], bfr[nf], acc[p][nf], 0, 0, 0);
  }

  // epilogue: 3 passes (q, k, v); q gets softmax over head_dim
  for (int p=0;p<3;p++){
    __syncthreads();
    #pragma unroll
    for (int nf=0;nf<4;nf++){
      int col = nf*16 + rr;
      float rv = rl[col];
      #pragma unroll
      for (int reg=0;reg<4;reg++){
        int rowl = w*16 + qw*4 + reg;
        Ds[rowl*72 + col] = f2bf(acc[p][nf][reg] * rv);
      }
    }
    __syncthreads();
    if (p==0){
      if (t < 256){
        int h = t>>6, n = t&63;
        float v[32];
        float m = -1e30f;
        #pragma unroll
        for (int d=0;d<32;d++){ v[d] = bf2f(Ds[(h*32+d)*72 + n]); m = fmaxf(m, v[d]); }
        float s = 0.f;
        #pragma unroll
        for (int d=0;d<32;d++){ v[d] = __expf(v[d]-m); s += v[d]; }
        float inv = SCALE_Q / s;
        #pragma unroll
        for (int d=0;d<32;d++) Ds[(h*32+d)*72 + n] = f2bf(v[d]*inv);
      }
      __syncthreads();
    }
    int ro = t>>2, seg = (t&3)*16;
    u16* dst = qkv + ((size_t)(b*OC3 + p*128 + ro))*NPIX + n0 + seg;
    *(int4*)dst     = *(const int4*)&Ds[ro*72 + seg];
    *(int4*)(dst+8) = *(const int4*)&Ds[ro*72 + seg + 8];
  }
}

// ---------------------------------------------------------------------------
// K2: k-row reduction only: M = max over (4 mem + 4096), inv = 1/sum(exp).
// kms[rid] = (M, inv); ksm[rid*4+m] = normalized memory-token weight.
// One wave per row, values held in registers (packed), two unpack passes.
// ---------------------------------------------------------------------------
__global__ __launch_bounds__(256) void k_kred(const u16* __restrict__ qkv,
                                              const float* __restrict__ memkv,
                                              float2* __restrict__ kms,
                                              float* __restrict__ ksm)
{
  const int rid = blockIdx.x*4 + (threadIdx.x>>6);
  const int lane = threadIdx.x & 63;
  const int d = rid & 31, h = (rid>>5)&3, b = rid>>7;
  const u16* p = qkv + (size_t)(b*OC3 + HID + h*HDIM + d)*NPIX;
  u32 buf[32];
  #pragma unroll
  for (int j=0;j<8;j++)
    *(int4*)&buf[j*4] = *(const int4*)(p + (size_t)(j*64+lane)*8);
  float m = -1e30f;
  #pragma unroll
  for (int i=0;i<32;i++){
    float lo = __uint_as_float(buf[i]<<16);
    float hi = __uint_as_float(buf[i]&0xffff0000u);
    m = fmaxf(m, fmaxf(lo, hi));
  }
  float mv[4];
  #pragma unroll
  for (int mm=0;mm<4;mm++){ mv[mm] = memkv[(h*HDIM+d)*NMEM + mm]; m = fmaxf(m, mv[mm]); }
  #pragma unroll
  for (int sh=1; sh<64; sh<<=1) m = fmaxf(m, __shfl_xor(m, sh, 64));
  float ssum = 0.f;
  #pragma unroll
  for (int i=0;i<32;i++){
    float lo = __uint_as_float(buf[i]<<16);
    float hi = __uint_as_float(buf[i]&0xffff0000u);
    ssum += __expf(lo-m) + __expf(hi-m);
  }
  #pragma unroll
  for (int sh=1; sh<64; sh<<=1) ssum += __shfl_xor(ssum, sh, 64);
  #pragma unroll
  for (int mm=0;mm<4;mm++) ssum += __expf(mv[mm]-m);
  float inv = 1.0f/ssum;
  if (lane==0) kms[rid] = make_float2(m, inv);
  if (lane<4) ksm[rid*NMEM + lane] = __expf(mv[lane]-m)*inv;
}

// ---------------------------------------------------------------------------
// K3: ctx[b,h,d,e] = sum_tokens exp(k[d,n]-M)*inv * v[e,n]  (16 n-splits)
// softmax applied on the fly during K staging (k never rewritten).
// ---------------------------------------------------------------------------
__global__ __launch_bounds__(64) void k_ctx(const u16* __restrict__ qkv,
                                            const float* __restrict__ memkv,
                                            const float* __restrict__ ksm,
                                            const float2* __restrict__ kms,
                                            float* __restrict__ ctxp)
{
  __shared__ float Ks[32][132];
  __shared__ float Vs[32][132];
  const int bh = blockIdx.x;                // 0..63
  const int s  = blockIdx.y;                // 0..15
  const int b = bh>>2, h = bh&3;
  const int t = threadIdx.x;
  const int d0 = (t>>3)*4, e0 = (t&7)*4;
  float acc[4][4] = {};
  if (s==0){
    #pragma unroll
    for (int m=0;m<4;m++){
      float km[4];
      #pragma unroll
      for (int pi=0;pi<4;pi++) km[pi] = ksm[(bh*HDIM + d0+pi)*NMEM + m];
      #pragma unroll
      for (int q=0;q<4;q++){
        float vm = memkv[((NHEAD+h)*HDIM + e0+q)*NMEM + m];
        #pragma unroll
        for (int pi=0;pi<4;pi++) acc[pi][q] += km[pi]*vm;
      }
    }
  }
  const u16* kb = qkv + (size_t)(b*OC3 +   HID + h*HDIM)*NPIX;
  const u16* vb = qkv + (size_t)(b*OC3 + 2*HID + h*HDIM)*NPIX;
  const int lr = t>>1, lseg = (t&1)*64;
  const float2 ms = kms[bh*HDIM + lr];
  for (int n0 = s*256; n0 < s*256+256; n0 += 128){
    const u16* kp = kb + (size_t)lr*NPIX + n0 + lseg;
    const u16* vp = vb + (size_t)lr*NPIX + n0 + lseg;
    #pragma unroll
    for (int u=0;u<8;u++){
      int4 kv = *(const int4*)(kp + u*8);
      int4 vv = *(const int4*)(vp + u*8);
      float kf[8], vf[8];
      unpack8(kv,kf); unpack8(vv,vf);
      #pragma unroll
      for (int i=0;i<8;i++) kf[i] = __expf(kf[i]-ms.x)*ms.y;
      *(float4*)&Ks[lr][lseg+u*8]   = make_float4(kf[0],kf[1],kf[2],kf[3]);
      *(float4*)&Ks[lr][lseg+u*8+4] = make_float4(kf[4],kf[5],kf[6],kf[7]);
      *(float4*)&Vs[lr][lseg+u*8]   = make_float4(vf[0],vf[1],vf[2],vf[3]);
      *(float4*)&Vs[lr][lseg+u*8+4] = make_float4(vf[4],vf[5],vf[6],vf[7]);
    }
    __syncthreads();
    #pragma unroll 4
    for (int nn=0;nn<128;nn+=4){
      float kq[4][4] __attribute__((aligned(16)));
      float vq[4][4] __attribute__((aligned(16)));
      #pragma unroll
      for (int pi=0;pi<4;pi++) *(float4*)kq[pi] = *(const float4*)&Ks[d0+pi][nn];
      #pragma unroll
      for (int q=0;q<4;q++)    *(float4*)vq[q]  = *(const float4*)&Vs[e0+q][nn];
      #pragma unroll
      for (int pi=0;pi<4;pi++)
        #pragma unroll
        for (int q=0;q<4;q++)
          acc[pi][q] += kq[pi][0]*vq[q][0] + kq[pi][1]*vq[q][1]
                      + kq[pi][2]*vq[q][2] + kq[pi][3]*vq[q][3];
    }
    __syncthreads();
  }
  #pragma unroll
  for (int pi=0;pi<4;pi++)
    *(float4*)(ctxp + (size_t)(s*64+bh)*1024 + (d0+pi)*32 + e0) =
      make_float4(acc[pi][0],acc[pi][1],acc[pi][2],acc[pi][3]);
}

__global__ __launch_bounds__(256) void k_ctxred(const float* __restrict__ ctxp,
                                                float* __restrict__ ctx)
{
  const int bh = blockIdx.x, t = threadIdx.x;
  float4 s = make_float4(0.f,0.f,0.f,0.f);
  #pragma unroll
  for (int sp=0; sp<16; sp++){
    float4 v = *(const float4*)(ctxp + (size_t)(sp*64+bh)*1024 + t*4);
    s.x+=v.x; s.y+=v.y; s.z+=v.z; s.w+=v.w;
  }
  *(float4*)(ctx + (size_t)bh*1024 + t*4) = s;
}

// ---------------------------------------------------------------------------
// K4: aoT[b,n,h*32+e] = sum_d ctx[b,h,d,e]*qs[b,h*32+d,n]  (q pre-softmaxed)
// ---------------------------------------------------------------------------
__global__ __launch_bounds__(256) void k_attnout(const u16* __restrict__ qkv,
                                                 const float* __restrict__ ctx,
                                                 u16* __restrict__ aoT)
{
  const int nc = blockIdx.x, h = blockIdx.y, b = blockIdx.z;
  const int bh = (b<<2) + h;
  const int n = nc*256 + threadIdx.x;
  const float* C = ctx + (size_t)bh*1024;
  const u16* qp = qkv + (size_t)(b*OC3 + h*HDIM)*NPIX + n;
  float qv[32];
  #pragma unroll
  for (int d=0;d<32;d++) qv[d] = bf2f(qp[(size_t)d*NPIX]);
  float res[32];
  #pragma unroll
  for (int eb=0;eb<8;eb++){
    float s0=0.f,s1=0.f,s2=0.f,s3=0.f;
    #pragma unroll
    for (int d=0;d<32;d++){
      float4 cv = *(const float4*)(C + d*32 + eb*4);
      float qd = qv[d];
      s0 += cv.x*qd; s1 += cv.y*qd; s2 += cv.z*qd; s3 += cv.w*qd;
    }
    res[eb*4+0]=s0; res[eb*4+1]=s1; res[eb*4+2]=s2; res[eb*4+3]=s3;
  }
  u16* op = aoT + ((size_t)b*NPIX + n)*HID + h*HDIM;
  #pragma unroll
  for (int i=0;i<4;i++){
    u32 pk[4];
    #pragma unroll
    for (int q=0;q<4;q++)
      pk[q] = (u32)f2bf(res[i*8+2*q]) | ((u32)f2bf(res[i*8+2*q+1])<<16);
    *(int4*)(op + i*8) = make_int4((int)pk[0],(int)pk[1],(int)pk[2],(int)pk[3]);
  }
}

// ---------------------------------------------------------------------------
// K5: out[b,c,n] = rms_c( wob[c,:] . aoT[b,n,:] + b_out ) * g_out  (bf16 MFMA)
// Tile 256c x 64n (full c per block -> in-block rms), 4 waves x (4x4 frags).
// ---------------------------------------------------------------------------
__global__ __launch_bounds__(256) void k_out(const u16* __restrict__ wob,
                                             const u16* __restrict__ aoT,
                                             const float* __restrict__ bout,
                                             const float* __restrict__ gout,
                                             float* __restrict__ out)
{
  __shared__ u16 As[256*32];      // [c][k]
  __shared__ u16 Bs[64*32];       // [n][k]
  __shared__ float ssql[4][64];
  const int t = threadIdx.x, w = t>>6, lane = t&63;
  const int n0 = blockIdx.x*64, b = blockIdx.y;
  const int qw = lane>>4, rr = lane&15;
  f32x4 acc[4][4];
  #pragma unroll
  for (int i=0;i<4;i++)
    #pragma unroll
    for (int j=0;j<4;j++) acc[i][j] = (f32x4){0.f,0.f,0.f,0.f};

  const u16* Bg = aoT + ((size_t)b*NPIX + n0)*HID;

  for (int k0=0; k0<HID; k0+=32){
    if (k0) __syncthreads();
    #pragma unroll
    for (int j=0;j<4;j++){
      int rb = w*64 + j*16;
      int row = rb + (lane>>2);
      int gc  = ((lane&3) - (row>>1)) & 3;
      async16(&As[rb*32], wob + (size_t)row*HID + k0 + gc*8);
    }
    {
      int rb = w*16;
      int row = rb + (lane>>2);
      int gc  = ((lane&3) - (row>>1)) & 3;
      async16(&Bs[rb*32], Bg + (size_t)row*HID + k0 + gc*8);
    }
    __syncthreads();
    bf16x8 af[4], bfr[4];
    #pragma unroll
    for (int mf=0;mf<4;mf++){
      int row = w*64 + mf*16 + rr;
      int s = (qw + (row>>1)) & 3;
      af[mf] = *(const bf16x8*)&As[row*32 + s*8];
    }
    #pragma unroll
    for (int nf=0;nf<4;nf++){
      int row = nf*16 + rr;
      int s = (qw + (row>>1)) & 3;
      bfr[nf] = *(const bf16x8*)&Bs[row*32 + s*8];
    }
    #pragma unroll
    for (int mf=0;mf<4;mf++)
      #pragma unroll
      for (int nf=0;nf<4;nf++)
        acc[mf][nf] = __builtin_amdgcn_mfma_f32_16x16x32_bf16(af[mf], bfr[nf], acc[mf][nf], 0, 0, 0);
  }
  __syncthreads();
  float pssq[4] = {0.f,0.f,0.f,0.f};
  #pragma unroll
  for (int mf=0;mf<4;mf++)
    #pragma unroll
    for (int reg=0;reg<4;reg++){
      int c = w*64 + mf*16 + qw*4 + reg;
      float bb = bout[c];
      #pragma unroll
      for (int nf=0;nf<4;nf++){
        float v = acc[mf][nf][reg] + bb;
        acc[mf][nf][reg] = v;
        pssq[nf] += v*v;
      }
    }
  #pragma unroll
  for (int nf=0;nf<4;nf++){
    pssq[nf] += __shfl_xor(pssq[nf], 16, 64);
    pssq[nf] += __shfl_xor(pssq[nf], 32, 64);
  }
  if (qw==0){
    #pragma unroll
    for (int nf=0;nf<4;nf++) ssql[w][nf*16+rr] = pssq[nf];
  }
  __syncthreads();
  float rv[4];
  #pragma unroll
  for (int nf=0;nf<4;nf++){
    int col = nf*16 + rr;
    float sm = ssql[0][col]+ssql[1][col]+ssql[2][col]+ssql[3][col];
    rv[nf] = 16.0f / fmaxf(sqrtf(sm), 1e-12f);
  }
  #pragma unroll
  for (int mf=0;mf<4;mf++)
    #pragma unroll
    for (int reg=0;reg<4;reg++){
      int c = w*64 + mf*16 + qw*4 + reg;
      float g = gout[c];
      float* po = out + ((size_t)(b*NCH + c))*NPIX + n0;
      #pragma unroll
      for (int nf=0;nf<4;nf++)
        po[nf*16 + rr] = acc[mf][nf][reg]*rv[nf]*g;
    }
}

// ---------------------------------------------------------------------------
extern "C" void kernel_launch(void* const* d_in, const int* in_sizes, int n_in,
                              void* d_out, int out_size, void* d_ws, size_t ws_size,
                              hipStream_t stream)
{
  const float* x     = (const float*)d_in[0];
  const float* gin   = (const float*)d_in[1];
  const float* memkv = (const float*)d_in[2];
  const float* wqkv  = (const float*)d_in[3];
  const float* wout  = (const float*)d_in[4];
  const float* bout  = (const float*)d_in[5];
  const float* gout  = (const float*)d_in[6];
  float* out = (float*)d_out;

  char* ws = (char*)d_ws;
  u16*    qkv  = (u16*)   (ws);                     // 50,331,648
  float*  ksm  = (float*) (ws + 50331648);          //     32,768
  float2* kms  = (float2*)(ws + 50364416);          //     16,384
  float*  ctxp = (float*) (ws + 50380800);          //  4,194,304
  float*  ctx  = (float*) (ws + 54575104);          //    262,144
  u16*    aoT  = (u16*)   (ws + 54837248);          // 16,777,216
  u16*    wqb  = (u16*)   (ws + 71614464);          //    196,608
  u16*    wob  = (u16*)   (ws + 71811072);          //     65,536  -> total 71,876,608

  hipLaunchKernelGGL(k_pack,   dim3(512),     dim3(256), 0, stream, wqkv, gin, wout, wqb, wob);
  hipLaunchKernelGGL(k_qkvx,   dim3(64,16),   dim3(512), 0, stream, x, wqb, qkv);
  hipLaunchKernelGGL(k_kred,   dim3(512),     dim3(256), 0, stream, qkv, memkv, kms, ksm);
  hipLaunchKernelGGL(k_ctx,    dim3(64,16),   dim3(64),  0, stream, qkv, memkv, ksm, kms, ctxp);
  hipLaunchKernelGGL(k_ctxred, dim3(64),      dim3(256), 0, stream, ctxp, ctx);
  hipLaunchKernelGGL(k_attnout,dim3(16,4,16), dim3(256), 0, stream, qkv, ctx, aoT);
  hipLaunchKernelGGL(k_out,    dim3(64,16),   dim3(256), 0, stream, wob, aoT, bout, gout, out);
}

// Round 5
// 200.368 us; speedup vs baseline: 2.2723x; 1.0567x over previous
//
#include <hip/hip_runtime.h>
#include <math.h>

typedef unsigned short u16;
typedef unsigned int u32;

#define NBATCH 16
#define NCH    256
#define NPIX   4096
#define NHEAD  4
#define HDIM   32
#define NMEM   4
#define HID    128
#define OC3    384
#define SCALE_Q 0.17677669529663687f

typedef __bf16 bf16x8 __attribute__((ext_vector_type(8)));
typedef float  f32x4  __attribute__((ext_vector_type(4)));

__device__ __forceinline__ float bf2f(u16 u){ return __uint_as_float(((u32)u)<<16); }
__device__ __forceinline__ u16 f2bf(float f){
  u32 x = __float_as_uint(f);
  x += 0x7fffu + ((x>>16)&1u);          // RNE
  return (u16)(x>>16);
}
__device__ __forceinline__ void unpack8(int4 v, float* o){
  u32 a=(u32)v.x, b=(u32)v.y, c=(u32)v.z, d=(u32)v.w;
  o[0]=__uint_as_float(a<<16); o[1]=__uint_as_float(a&0xffff0000u);
  o[2]=__uint_as_float(b<<16); o[3]=__uint_as_float(b&0xffff0000u);
  o[4]=__uint_as_float(c<<16); o[5]=__uint_as_float(c&0xffff0000u);
  o[6]=__uint_as_float(d<<16); o[7]=__uint_as_float(d&0xffff0000u);
}

// ---------------------------------------------------------------------------
// K0: pack wqb[o][c] = bf16(w_qkv*g_in), wob[c][e] = bf16(w_out)
// ---------------------------------------------------------------------------
__global__ __launch_bounds__(256) void k_pack(const float* __restrict__ wqkv,
                                              const float* __restrict__ gin,
                                              const float* __restrict__ wout,
                                              u16* __restrict__ wqb,
                                              u16* __restrict__ wob)
{
  int i = blockIdx.x*256 + threadIdx.x;
  if (i < OC3*NCH){ int c = i & 255; wqb[i] = f2bf(wqkv[i]*gin[c]); }
  else { int j = i - OC3*NCH; wob[j] = f2bf(wout[j]); }
}

// ---------------------------------------------------------------------------
// K1: fused rms-norm + transpose + QKV GEMM (bf16 MFMA) + q-softmax.
// Tile 384(o) x 64(n), 8 waves. A-fragments loaded DIRECT from global
// (weights are L2-resident; no LDS staging, no K-loop barriers).
// Ds repack buffer is unioned onto Bx (dead after last MFMA).
// ---------------------------------------------------------------------------
__global__ __launch_bounds__(512) void k_qkvx(const float* __restrict__ x,
                                              const u16* __restrict__ wqb,
                                              u16* __restrict__ qkv)
{
  __shared__ u16 BxDs[64*264];    // Bx: [n][c] bf16 stride 264; epilogue: Ds[128][72]
  __shared__ float ssqp[8][64];
  __shared__ float rl[64];
  u16* Ds = BxDs;
  const int t = threadIdx.x, w = t>>6, lane = t&63;
  const int n0 = blockIdx.x*64, b = blockIdx.y;
  const int qw = lane>>4, rr = lane&15;

  // phase 1: load x (coalesced), bf16-transpose into Bx, per-n sum-of-squares
  {
    const float* xp = x + ((size_t)b*NCH + w*32)*NPIX + n0 + lane;
    float ssq = 0.f;
    #pragma unroll
    for (int j=0;j<4;j++){
      u32 pk[4];
      #pragma unroll
      for (int q=0;q<4;q++){
        float v0 = xp[(size_t)(j*8+2*q  )*NPIX];
        float v1 = xp[(size_t)(j*8+2*q+1)*NPIX];
        ssq += v0*v0 + v1*v1;
        pk[q] = (u32)f2bf(v0) | ((u32)f2bf(v1)<<16);
      }
      *(int4*)&BxDs[lane*264 + w*32 + j*8] = make_int4((int)pk[0],(int)pk[1],(int)pk[2],(int)pk[3]);
    }
    ssqp[w][lane] = ssq;
  }
  __syncthreads();
  if (t < 64){
    float s = 0.f;
    #pragma unroll
    for (int g=0;g<8;g++) s += ssqp[g][t];
    rl[t] = 16.0f / fmaxf(sqrtf(s), 1e-12f);
  }

  f32x4 acc[3][4];
  #pragma unroll
  for (int p=0;p<3;p++)
    #pragma unroll
    for (int nf=0;nf<4;nf++) acc[p][nf] = (f32x4){0.f,0.f,0.f,0.f};

  // barrier-free K-loop: A-frags from global (L2), B-frags from Bx
  const u16* a0 = wqb + (size_t)(0*128 + w*16 + rr)*NCH + qw*8;
  const u16* a1 = wqb + (size_t)(1*128 + w*16 + rr)*NCH + qw*8;
  const u16* a2 = wqb + (size_t)(2*128 + w*16 + rr)*NCH + qw*8;
  #pragma unroll
  for (int c0=0; c0<NCH; c0+=32){
    bf16x8 af0 = *(const bf16x8*)(a0 + c0);
    bf16x8 af1 = *(const bf16x8*)(a1 + c0);
    bf16x8 af2 = *(const bf16x8*)(a2 + c0);
    bf16x8 bfr[4];
    #pragma unroll
    for (int nf=0;nf<4;nf++)
      bfr[nf] = *(const bf16x8*)&BxDs[(nf*16+rr)*264 + c0 + qw*8];
    #pragma unroll
    for (int nf=0;nf<4;nf++){
      acc[0][nf] = __builtin_amdgcn_mfma_f32_16x16x32_bf16(af0, bfr[nf], acc[0][nf], 0, 0, 0);
      acc[1][nf] = __builtin_amdgcn_mfma_f32_16x16x32_bf16(af1, bfr[nf], acc[1][nf], 0, 0, 0);
      acc[2][nf] = __builtin_amdgcn_mfma_f32_16x16x32_bf16(af2, bfr[nf], acc[2][nf], 0, 0, 0);
    }
  }

  // epilogue: 3 passes (q, k, v); q gets softmax over head_dim
  for (int p=0;p<3;p++){
    __syncthreads();
    #pragma unroll
    for (int nf=0;nf<4;nf++){
      int col = nf*16 + rr;
      float rv = rl[col];
      #pragma unroll
      for (int reg=0;reg<4;reg++){
        int rowl = w*16 + qw*4 + reg;
        Ds[rowl*72 + col] = f2bf(acc[p][nf][reg] * rv);
      }
    }
    __syncthreads();
    if (p==0){
      if (t < 256){
        int h = t>>6, n = t&63;
        float v[32];
        float m = -1e30f;
        #pragma unroll
        for (int d=0;d<32;d++){ v[d] = bf2f(Ds[(h*32+d)*72 + n]); m = fmaxf(m, v[d]); }
        float s = 0.f;
        #pragma unroll
        for (int d=0;d<32;d++){ v[d] = __expf(v[d]-m); s += v[d]; }
        float inv = SCALE_Q / s;
        #pragma unroll
        for (int d=0;d<32;d++) Ds[(h*32+d)*72 + n] = f2bf(v[d]*inv);
      }
      __syncthreads();
    }
    int ro = t>>2, seg = (t&3)*16;
    u16* dst = qkv + ((size_t)(b*OC3 + p*128 + ro))*NPIX + n0 + seg;
    *(int4*)dst     = *(const int4*)&Ds[ro*72 + seg];
    *(int4*)(dst+8) = *(const int4*)&Ds[ro*72 + seg + 8];
  }
}

// ---------------------------------------------------------------------------
// K2: k-row reduction: M = max over (4 mem + 4096), inv = 1/sum(exp).
// ---------------------------------------------------------------------------
__global__ __launch_bounds__(256) void k_kred(const u16* __restrict__ qkv,
                                              const float* __restrict__ memkv,
                                              float2* __restrict__ kms,
                                              float* __restrict__ ksm)
{
  const int rid = blockIdx.x*4 + (threadIdx.x>>6);
  const int lane = threadIdx.x & 63;
  const int d = rid & 31, h = (rid>>5)&3, b = rid>>7;
  const u16* p = qkv + (size_t)(b*OC3 + HID + h*HDIM + d)*NPIX;
  u32 buf[32];
  #pragma unroll
  for (int j=0;j<8;j++)
    *(int4*)&buf[j*4] = *(const int4*)(p + (size_t)(j*64+lane)*8);
  float m = -1e30f;
  #pragma unroll
  for (int i=0;i<32;i++){
    float lo = __uint_as_float(buf[i]<<16);
    float hi = __uint_as_float(buf[i]&0xffff0000u);
    m = fmaxf(m, fmaxf(lo, hi));
  }
  float mv[4];
  #pragma unroll
  for (int mm=0;mm<4;mm++){ mv[mm] = memkv[(h*HDIM+d)*NMEM + mm]; m = fmaxf(m, mv[mm]); }
  #pragma unroll
  for (int sh=1; sh<64; sh<<=1) m = fmaxf(m, __shfl_xor(m, sh, 64));
  float ssum = 0.f;
  #pragma unroll
  for (int i=0;i<32;i++){
    float lo = __uint_as_float(buf[i]<<16);
    float hi = __uint_as_float(buf[i]&0xffff0000u);
    ssum += __expf(lo-m) + __expf(hi-m);
  }
  #pragma unroll
  for (int sh=1; sh<64; sh<<=1) ssum += __shfl_xor(ssum, sh, 64);
  #pragma unroll
  for (int mm=0;mm<4;mm++) ssum += __expf(mv[mm]-m);
  float inv = 1.0f/ssum;
  if (lane==0) kms[rid] = make_float2(m, inv);
  if (lane<4) ksm[rid*NMEM + lane] = __expf(mv[lane]-m)*inv;
}

// ---------------------------------------------------------------------------
// K3: ctx[b,h,d,e] = sum_tokens exp(k[d,n]-M)*inv * v[e,n]  (32 n-splits)
// ---------------------------------------------------------------------------
__global__ __launch_bounds__(64) void k_ctx(const u16* __restrict__ qkv,
                                            const float* __restrict__ memkv,
                                            const float* __restrict__ ksm,
                                            const float2* __restrict__ kms,
                                            float* __restrict__ ctxp)
{
  __shared__ float Ks[32][132];
  __shared__ float Vs[32][132];
  const int bh = blockIdx.x;                // 0..63
  const int s  = blockIdx.y;                // 0..31
  const int b = bh>>2, h = bh&3;
  const int t = threadIdx.x;
  const int d0 = (t>>3)*4, e0 = (t&7)*4;
  float acc[4][4] = {};
  if (s==0){
    #pragma unroll
    for (int m=0;m<4;m++){
      float km[4];
      #pragma unroll
      for (int pi=0;pi<4;pi++) km[pi] = ksm[(bh*HDIM + d0+pi)*NMEM + m];
      #pragma unroll
      for (int q=0;q<4;q++){
        float vm = memkv[((NHEAD+h)*HDIM + e0+q)*NMEM + m];
        #pragma unroll
        for (int pi=0;pi<4;pi++) acc[pi][q] += km[pi]*vm;
      }
    }
  }
  const u16* kb = qkv + (size_t)(b*OC3 +   HID + h*HDIM)*NPIX;
  const u16* vb = qkv + (size_t)(b*OC3 + 2*HID + h*HDIM)*NPIX;
  const int lr = t>>1, lseg = (t&1)*64;
  const float2 ms = kms[bh*HDIM + lr];
  const int n0 = s*128;
  {
    const u16* kp = kb + (size_t)lr*NPIX + n0 + lseg;
    const u16* vp = vb + (size_t)lr*NPIX + n0 + lseg;
    #pragma unroll
    for (int u=0;u<8;u++){
      int4 kv = *(const int4*)(kp + u*8);
      int4 vv = *(const int4*)(vp + u*8);
      float kf[8], vf[8];
      unpack8(kv,kf); unpack8(vv,vf);
      #pragma unroll
      for (int i=0;i<8;i++) kf[i] = __expf(kf[i]-ms.x)*ms.y;
      *(float4*)&Ks[lr][lseg+u*8]   = make_float4(kf[0],kf[1],kf[2],kf[3]);
      *(float4*)&Ks[lr][lseg+u*8+4] = make_float4(kf[4],kf[5],kf[6],kf[7]);
      *(float4*)&Vs[lr][lseg+u*8]   = make_float4(vf[0],vf[1],vf[2],vf[3]);
      *(float4*)&Vs[lr][lseg+u*8+4] = make_float4(vf[4],vf[5],vf[6],vf[7]);
    }
    __syncthreads();
    #pragma unroll 4
    for (int nn=0;nn<128;nn+=4){
      float kq[4][4] __attribute__((aligned(16)));
      float vq[4][4] __attribute__((aligned(16)));
      #pragma unroll
      for (int pi=0;pi<4;pi++) *(float4*)kq[pi] = *(const float4*)&Ks[d0+pi][nn];
      #pragma unroll
      for (int q=0;q<4;q++)    *(float4*)vq[q]  = *(const float4*)&Vs[e0+q][nn];
      #pragma unroll
      for (int pi=0;pi<4;pi++)
        #pragma unroll
        for (int q=0;q<4;q++)
          acc[pi][q] += kq[pi][0]*vq[q][0] + kq[pi][1]*vq[q][1]
                      + kq[pi][2]*vq[q][2] + kq[pi][3]*vq[q][3];
    }
  }
  #pragma unroll
  for (int pi=0;pi<4;pi++)
    *(float4*)(ctxp + (size_t)(s*64+bh)*1024 + (d0+pi)*32 + e0) =
      make_float4(acc[pi][0],acc[pi][1],acc[pi][2],acc[pi][3]);
}

__global__ __launch_bounds__(256) void k_ctxred(const float* __restrict__ ctxp,
                                                float* __restrict__ ctx)
{
  const int bh = blockIdx.x, t = threadIdx.x;
  float4 s = make_float4(0.f,0.f,0.f,0.f);
  #pragma unroll
  for (int sp=0; sp<32; sp++){
    float4 v = *(const float4*)(ctxp + (size_t)(sp*64+bh)*1024 + t*4);
    s.x+=v.x; s.y+=v.y; s.z+=v.z; s.w+=v.w;
  }
  *(float4*)(ctx + (size_t)bh*1024 + t*4) = s;
}

// ---------------------------------------------------------------------------
// K4 (fused attnout + w_out + rms): per (b, 64-n tile):
//   PV MFMA: ao[e,n] = sum_d ctx[h,d,e]*q[h,d,n]  (ctx->bf16 LDS A, q LDS-T B)
//   then out = rms_c( wob . ao + b_out ) * g_out   (A direct from global/L2)
// ---------------------------------------------------------------------------
__global__ __launch_bounds__(256) void k_fout(const u16* __restrict__ qkv,
                                              const float* __restrict__ ctx,
                                              const u16* __restrict__ wob,
                                              const float* __restrict__ bout,
                                              const float* __restrict__ gout,
                                              float* __restrict__ out)
{
  __shared__ u16 Cb[4*32*40];     // [h][e][d], stride 40
  __shared__ u16 Qs[64*136];      // [n][h*32+d]
  __shared__ u16 Ao[64*136];      // [n][e(hid)]
  __shared__ float ssql[4][64];
  const int t = threadIdx.x, w = t>>6, lane = t&63;
  const int n0 = blockIdx.x*64, b = blockIdx.y;
  const int qw = lane>>4, rr = lane&15;

  // stage ctx -> Cb bf16 transposed [h][e][d]
  {
    const float4* c4 = (const float4*)(ctx + (size_t)b*4096);
    const int d = (t>>3)&31, e0 = (t&7)*4;
    #pragma unroll
    for (int h=0;h<4;h++){
      float4 v = c4[t + h*256];
      Cb[(h*32+e0+0)*40 + d] = f2bf(v.x);
      Cb[(h*32+e0+1)*40 + d] = f2bf(v.y);
      Cb[(h*32+e0+2)*40 + d] = f2bf(v.z);
      Cb[(h*32+e0+3)*40 + d] = f2bf(v.w);
    }
  }
  // stage q -> Qs[n][o] transposed (o = h*32+d in 0..128)
  {
    const int ro = t>>1, nh = (t&1)*32;
    const u16* qp = qkv + ((size_t)(b*OC3 + ro))*NPIX + n0 + nh;
    u16 tmp[32];
    *(int4*)&tmp[0]  = *(const int4*)(qp);
    *(int4*)&tmp[8]  = *(const int4*)(qp+8);
    *(int4*)&tmp[16] = *(const int4*)(qp+16);
    *(int4*)&tmp[24] = *(const int4*)(qp+24);
    #pragma unroll
    for (int j=0;j<32;j++) Qs[(nh+j)*136 + ro] = tmp[j];
  }
  __syncthreads();

  // PV MFMA: wave w owns n-frag w (n = w*16 + rr)
  f32x4 pv[4][2];
  #pragma unroll
  for (int h=0;h<4;h++){
    bf16x8 bq = *(const bf16x8*)&Qs[(w*16+rr)*136 + h*32 + qw*8];
    #pragma unroll
    for (int ef=0;ef<2;ef++){
      bf16x8 af = *(const bf16x8*)&Cb[(h*32 + ef*16 + rr)*40 + qw*8];
      f32x4 z = (f32x4){0.f,0.f,0.f,0.f};
      pv[h][ef] = __builtin_amdgcn_mfma_f32_16x16x32_bf16(af, bq, z, 0, 0, 0);
    }
  }
  // write ao -> Ao[n][e] (C-layout: col n = w*16+rr, rows e = qw*4+reg)
  #pragma unroll
  for (int h=0;h<4;h++)
    #pragma unroll
    for (int ef=0;ef<2;ef++){
      u32 lohi0 = (u32)f2bf(pv[h][ef][0]) | ((u32)f2bf(pv[h][ef][1])<<16);
      u32 lohi1 = (u32)f2bf(pv[h][ef][2]) | ((u32)f2bf(pv[h][ef][3])<<16);
      *(int2*)&Ao[(w*16+rr)*136 + h*32 + ef*16 + qw*4] = make_int2((int)lohi0,(int)lohi1);
    }
  __syncthreads();

  // w_out GEMM: K=128 over e; A = wob[c][e] direct from global (L2-hot)
  f32x4 acc[4][4];
  #pragma unroll
  for (int i=0;i<4;i++)
    #pragma unroll
    for (int j=0;j<4;j++) acc[i][j] = (f32x4){0.f,0.f,0.f,0.f};
  #pragma unroll
  for (int k0=0; k0<HID; k0+=32){
    bf16x8 af[4], bfr[4];
    #pragma unroll
    for (int mf=0;mf<4;mf++)
      af[mf] = *(const bf16x8*)&wob[(size_t)(w*64 + mf*16 + rr)*HID + k0 + qw*8];
    #pragma unroll
    for (int nf=0;nf<4;nf++)
      bfr[nf] = *(const bf16x8*)&Ao[(nf*16+rr)*136 + k0 + qw*8];
    #pragma unroll
    for (int mf=0;mf<4;mf++)
      #pragma unroll
      for (int nf=0;nf<4;nf++)
        acc[mf][nf] = __builtin_amdgcn_mfma_f32_16x16x32_bf16(af[mf], bfr[nf], acc[mf][nf], 0, 0, 0);
  }
  // bias + column sum-of-squares (full 256 c in this block)
  float pssq[4] = {0.f,0.f,0.f,0.f};
  #pragma unroll
  for (int mf=0;mf<4;mf++)
    #pragma unroll
    for (int reg=0;reg<4;reg++){
      int c = w*64 + mf*16 + qw*4 + reg;
      float bb = bout[c];
      #pragma unroll
      for (int nf=0;nf<4;nf++){
        float v = acc[mf][nf][reg] + bb;
        acc[mf][nf][reg] = v;
        pssq[nf] += v*v;
      }
    }
  #pragma unroll
  for (int nf=0;nf<4;nf++){
    pssq[nf] += __shfl_xor(pssq[nf], 16, 64);
    pssq[nf] += __shfl_xor(pssq[nf], 32, 64);
  }
  if (qw==0){
    #pragma unroll
    for (int nf=0;nf<4;nf++) ssql[w][nf*16+rr] = pssq[nf];
  }
  __syncthreads();
  float rv[4];
  #pragma unroll
  for (int nf=0;nf<4;nf++){
    int col = nf*16 + rr;
    float sm = ssql[0][col]+ssql[1][col]+ssql[2][col]+ssql[3][col];
    rv[nf] = 16.0f / fmaxf(sqrtf(sm), 1e-12f);
  }
  #pragma unroll
  for (int mf=0;mf<4;mf++)
    #pragma unroll
    for (int reg=0;reg<4;reg++){
      int c = w*64 + mf*16 + qw*4 + reg;
      float g = gout[c];
      float* po = out + ((size_t)(b*NCH + c))*NPIX + n0;
      #pragma unroll
      for (int nf=0;nf<4;nf++)
        po[nf*16 + rr] = acc[mf][nf][reg]*rv[nf]*g;
    }
}

// ---------------------------------------------------------------------------
extern "C" void kernel_launch(void* const* d_in, const int* in_sizes, int n_in,
                              void* d_out, int out_size, void* d_ws, size_t ws_size,
                              hipStream_t stream)
{
  const float* x     = (const float*)d_in[0];
  const float* gin   = (const float*)d_in[1];
  const float* memkv = (const float*)d_in[2];
  const float* wqkv  = (const float*)d_in[3];
  const float* wout  = (const float*)d_in[4];
  const float* bout  = (const float*)d_in[5];
  const float* gout  = (const float*)d_in[6];
  float* out = (float*)d_out;

  char* ws = (char*)d_ws;
  u16*    qkv  = (u16*)   (ws);                     // 50,331,648
  float*  ksm  = (float*) (ws + 50331648);          //     32,768
  float2* kms  = (float2*)(ws + 50364416);          //     16,384
  float*  ctxp = (float*) (ws + 50380800);          //  8,388,608
  float*  ctx  = (float*) (ws + 58769408);          //    262,144
  u16*    wqb  = (u16*)   (ws + 59031552);          //    196,608
  u16*    wob  = (u16*)   (ws + 59228160);          //     65,536  -> total 59,293,696

  hipLaunchKernelGGL(k_pack,   dim3(512),   dim3(256), 0, stream, wqkv, gin, wout, wqb, wob);
  hipLaunchKernelGGL(k_qkvx,   dim3(64,16), dim3(512), 0, stream, x, wqb, qkv);
  hipLaunchKernelGGL(k_kred,   dim3(512),   dim3(256), 0, stream, qkv, memkv, kms, ksm);
  hipLaunchKernelGGL(k_ctx,    dim3(64,32), dim3(64),  0, stream, qkv, memkv, ksm, kms, ctxp);
  hipLaunchKernelGGL(k_ctxred, dim3(64),    dim3(256), 0, stream, ctxp, ctx);
  hipLaunchKernelGGL(k_fout,   dim3(64,16), dim3(256), 0, stream, qkv, ctx, wob, bout, gout, out);
}